// Round 11
// baseline (363.120 us; speedup 1.0000x reference)
//
#include <hip/hip_runtime.h>
#include <hip/hip_bf16.h>
#include <cstdint>
#include <cstddef>

typedef __bf16 bf16;
typedef __attribute__((ext_vector_type(4))) float f32x4;
typedef __attribute__((ext_vector_type(8))) __bf16 bf16x8;
typedef __attribute__((ext_vector_type(4))) __bf16 bf16x4;

// ---------------- constants ----------------
#define T_TOKENS 8192
#define D_MODEL  1024
#define D_FF     2048
#define N_EXP    8
#define MAX_ROWS 17408   // 16384 + 8*128 padding
#define MAX_MT   136     // max m-tiles of 128 (8 XCD chunks of 17)

// ctrl layout (int indices): numTiles[16], pstart[32..40],
// tileExpert[64..199], tileRow[256..391]

__device__ __forceinline__ void gload16(const void* g, void* l) {
    __builtin_amdgcn_global_load_lds((const __attribute__((address_space(1))) void*)g,
                                     (__attribute__((address_space(3))) void*)l, 16, 0, 0);
}

// ---------------- fused prep: weight transposes + x convert + dispatch build ----
// grid (8,32,29), 256 threads.
//   z in [0,8):   W1 expert z    -> wc even 16-col blocks (mode 1)  [x<8, y<16]
//   z in [8,16):  W2 expert z-8  -> wc odd 16-col blocks (mode 2)   [x<8, y<16]
//   z in [16,24): W3 expert z-16 -> w3t plain (mode 0)              [x<4, y<32]
//   z in [24,28): cvtx, 256 virtual blocks per slice, 8192 elems each
//   z == 28, block (0,0): dispatch build (count/scan/scatter/pad) in one block.
//
// Transpose: per block a 64-row x 256-col strip, 4 sub-tiles of 64x64.
// Staging via global_load_lds with PRE-SWIZZLED SOURCE (linear LDS dest):
//   LDS[row][slot] (16B fp32 quads) = global quad (slot ^ swz(row)),
//   swz(row) = (row&7) ^ ((row>>3)&7).
// Read phase applies the same XOR; 8 same-column lanes -> 8 distinct bank
// groups (2 lanes/bank over the wave = free, m136).
__global__ __launch_bounds__(256)
void prep_kernel(const float* __restrict__ x, bf16* __restrict__ xb,
                 const float* __restrict__ w1, const float* __restrict__ w2,
                 const float* __restrict__ w3, bf16* __restrict__ wc,
                 bf16* __restrict__ w3t,
                 const int* __restrict__ ei, const float* __restrict__ ew,
                 int* __restrict__ ctrl, int* __restrict__ tokenId,
                 float* __restrict__ rowW, int* __restrict__ rowOf) {
    const int z = blockIdx.z;
    const int t = threadIdx.x;

    if (z >= 24) {
        if (z == 28) {
            // ---- dispatch build: single block ----
            if (blockIdx.x != 0 || blockIdx.y != 0) return;
            __shared__ int lc[N_EXP], cur[N_EXP], ps[N_EXP], padS[N_EXP], padE[N_EXP];
            if (t < N_EXP) { lc[t] = 0; cur[t] = 0; }
            __syncthreads();
            for (int i = t; i < T_TOKENS * 2; i += 256)
                atomicAdd(&lc[ei[i]], 1);
            __syncthreads();
            if (t == 0) {
                int s = 0, nt = 0;
                for (int e = 0; e < N_EXP; ++e) {
                    ps[e] = s;
                    ctrl[32 + e] = s;
                    int cnt = lc[e];
                    int tiles = (cnt + 127) >> 7;
                    for (int i = 0; i < tiles; ++i) {
                        ctrl[64 + nt] = e; ctrl[256 + nt] = s + (i << 7); ++nt;
                    }
                    padS[e] = s + cnt; padE[e] = s + (tiles << 7);
                    s += tiles << 7;
                }
                ctrl[16] = nt;
            }
            __syncthreads();
            for (int i = t; i < T_TOKENS * 2; i += 256) {
                int e = ei[i];
                int pos = atomicAdd(&cur[e], 1);
                int r = ps[e] + pos;
                tokenId[r] = i >> 1;
                rowW[r] = ew[i];
                rowOf[i] = r;
            }
            for (int e = 0; e < N_EXP; ++e)
                for (int r = padS[e] + t; r < padE[e]; r += 256) {
                    tokenId[r] = 0; rowW[r] = 0.f;
                }
            return;
        }
        // ---- cvtx: x fp32 -> xb bf16, 32 elems/thread (8192/block) ----
        int bid = (z - 24) * 256 + blockIdx.y * 8 + blockIdx.x;
#pragma unroll
        for (int p = 0; p < 4; ++p) {
            int i = bid * 8192 + p * 2048 + t * 8;
            float4 v0 = *(const float4*)(x + i);
            float4 v1 = *(const float4*)(x + i + 4);
            bf16x8 o;
            o[0] = (bf16)v0.x; o[1] = (bf16)v0.y; o[2] = (bf16)v0.z; o[3] = (bf16)v0.w;
            o[4] = (bf16)v1.x; o[5] = (bf16)v1.y; o[6] = (bf16)v1.z; o[7] = (bf16)v1.w;
            *(bf16x8*)(xb + i) = o;
        }
        return;
    }

    // ---- tconv: fp32 [R][C] -> bf16 [f(C)][R] for one expert, 64x256 strip ----
    int R, C, mode;
    const float* src;
    bf16* dst;
    if (z < 8)       { R = D_MODEL; C = D_FF;    mode = 1; src = w1 + (size_t)z * R * C;        dst = wc  + (size_t)z * 4096 * 1024; }
    else if (z < 16) { R = D_MODEL; C = D_FF;    mode = 2; src = w2 + (size_t)(z - 8) * R * C;  dst = wc  + (size_t)(z - 8) * 4096 * 1024; }
    else             { R = D_FF;    C = D_MODEL; mode = 0; src = w3 + (size_t)(z - 16) * R * C; dst = w3t + (size_t)(z - 16) * D_FF * D_MODEL; }
    const int c0 = blockIdx.x * 256, r0 = blockIdx.y * 64;
    if (c0 >= C || r0 >= R) return;

    __shared__ char tl[16384];   // fp32 [64 rows][16 slots x 16B], source-swizzled

    // per-thread constants for staging: wi = p*256 + t
    const int row_[4] = { (0 * 256 + t) >> 4, (1 * 256 + t) >> 4, (2 * 256 + t) >> 4, (3 * 256 + t) >> 4 };
    const int slot_[4] = { t & 15, t & 15, t & 15, t & 15 };  // (p*256+t)&15 == t&15

    for (int st = 0; st < 4; ++st) {
#pragma unroll
        for (int p = 0; p < 4; ++p) {
            int wi = p * 256 + t;
            int row = row_[p];
            int sq = slot_[p] ^ (row & 7) ^ ((row >> 3) & 7);  // source col-quad
            gload16(src + (size_t)(r0 + row) * C + c0 + st * 64 + sq * 4,
                    tl + wi * 16);
        }
        __syncthreads();   // drains vmcnt before reads
#pragma unroll
        for (int p = 0; p < 2; ++p) {
            int wi = p * 256 + t;
            int cl = wi >> 3, rs = wi & 7;
            int c = c0 + st * 64 + cl;
            int dcol = (mode == 0) ? c : (((c >> 4) << 5) + ((mode == 2) ? 16 : 0) + (c & 15));
            bf16x8 ov;
#pragma unroll
            for (int j = 0; j < 8; ++j) {
                int r = rs * 8 + j;
                int sp = (cl >> 2) ^ (r & 7) ^ rs;   // (r>>3)&7 == rs
                float f = *(const float*)(tl + r * 256 + sp * 16 + (cl & 3) * 4);
                ov[j] = (bf16)f;
            }
            *(bf16x8*)(dst + (size_t)dcol * R + r0 + rs * 8) = ov;
        }
        __syncthreads();   // all reads done before next sub-tile overwrites
    }
}

// ---------------- GEMM stage 1: H = silu(X Wc_even) * (X Wc_odd), gathered rows ----
// Combined B: wc [E][4096][1024] bf16 (row = combined col, K contiguous).
// m97-style 2-barrier single-buffer loop; 3 blocks/CU.
// Grid: 1D 4352 blocks, XCD-locality swizzle (xcd = L&7 owns m-tiles chunk).
__global__ __launch_bounds__(256, 3)
void gemm1_kernel(const bf16* __restrict__ xb, const bf16* __restrict__ wc,
                  bf16* __restrict__ H, const int* __restrict__ ctrl,
                  const int* __restrict__ tokenId) {
    const int L = blockIdx.x;
    const int xcd = L & 7;
    const int w = L >> 3;                 // 0..543
    const int mt = xcd * 17 + (w % 17);   // 0..135
    const int n0 = (w / 17) * 128;        // combined-col tile base (0..4095)
    if (mt >= ctrl[16]) return;
    const int e = ctrl[64 + mt];
    const int rowBase = ctrl[256 + mt];

    __shared__ char lds[32768];        // A: [0,16384)  B: [16384,32768)

    const int tid = threadIdx.x, lane = tid & 63;
    const int wm = (tid >> 7) & 1, wn = (tid >> 6) & 1;

    const bf16* wb = wc + (size_t)e * 4096 * 1024;

    const bf16* aSrc[4]; const bf16* bSrc[4]; int dstOff[4];
#pragma unroll
    for (int rd = 0; rd < 4; ++rd) {
        int o = rd * 4096 + tid * 16;
        int r = o >> 7;                    // row 0..127
        int c2 = ((o >> 4) & 7) ^ (r & 7); // pre-swizzled source slot
        dstOff[rd] = o;
        int tok = tokenId[rowBase + r];
        aSrc[rd] = xb + (size_t)tok * D_MODEL + c2 * 8;
        bSrc[rd] = wb + (size_t)(n0 + r) * D_MODEL + c2 * 8;
    }

    f32x4 acc[4][4];
#pragma unroll
    for (int m = 0; m < 4; ++m)
#pragma unroll
        for (int n = 0; n < 4; ++n) acc[m][n] = (f32x4){0.f, 0.f, 0.f, 0.f};

    for (int kt = 0; kt < D_MODEL / 64; ++kt) {
#pragma unroll
        for (int rd = 0; rd < 4; ++rd) {
            gload16(aSrc[rd] + kt * 64, lds + dstOff[rd]);
            gload16(bSrc[rd] + kt * 64, lds + 16384 + dstOff[rd]);
        }
        __syncthreads();   // drains vmcnt before any wave reads
#pragma unroll
        for (int ks = 0; ks < 2; ++ks) {
            bf16x8 af[4], bfr[4];
            int c2 = ks * 4 + (lane >> 4);
#pragma unroll
            for (int m = 0; m < 4; ++m) {
                int r = wm * 64 + m * 16 + (lane & 15);
                af[m] = *(const bf16x8*)(lds + r * 128 + ((c2 ^ (r & 7)) << 4));
            }
#pragma unroll
            for (int n = 0; n < 4; ++n) {
                int r = wn * 64 + n * 16 + (lane & 15);
                bfr[n] = *(const bf16x8*)(lds + 16384 + r * 128 + ((c2 ^ (r & 7)) << 4));
            }
#pragma unroll
            for (int m = 0; m < 4; ++m)
#pragma unroll
                for (int n = 0; n < 4; ++n)
                    acc[m][n] = __builtin_amdgcn_mfma_f32_16x16x32_bf16(af[m], bfr[n], acc[m][n], 0, 0, 0);
        }
        __syncthreads();   // all waves done reading before next stage overwrites
    }

    // epilogue: n-frag pairs (0,1)=(g,v) and (2,3)=(g,v); H col = (n0>>1)+wn*32+(pair?16:0)+(lane&15)
#pragma unroll
    for (int m = 0; m < 4; ++m) {
#pragma unroll
        for (int j = 0; j < 4; ++j) {
            int rl = wm * 64 + m * 16 + (lane >> 4) * 4 + j;
            bf16* hb = H + (size_t)(rowBase + rl) * D_FF + (n0 >> 1) + wn * 32 + (lane & 15);
            {
                float g = acc[m][0][j], v = acc[m][1][j];
                hb[0] = (bf16)((g / (1.f + __expf(-g))) * v);
            }
            {
                float g = acc[m][2][j], v = acc[m][3][j];
                hb[16] = (bf16)((g / (1.f + __expf(-g))) * v);
            }
        }
    }
}

// ---------------- GEMM stage 2: O2[row] = w[row] * (H[row] @ W3) ----------------
// Grid: 1D 1088 blocks. XCD swizzle, n-minor within chunk.
__global__ __launch_bounds__(256, 3)
void gemm2_kernel(const bf16* __restrict__ H, const bf16* __restrict__ w3t,
                  bf16* __restrict__ O2, const int* __restrict__ ctrl,
                  const float* __restrict__ rowW) {
    const int L = blockIdx.x;
    const int xcd = L & 7;
    const int w = L >> 3;                 // 0..135
    const int n0 = (w & 7) * 128;
    const int mt = xcd * 17 + (w >> 3);   // 0..135
    if (mt >= ctrl[16]) return;
    const int e = ctrl[64 + mt];
    const int rowBase = ctrl[256 + mt];

    __shared__ char lds[32768];

    const int tid = threadIdx.x, lane = tid & 63;
    const int wm = (tid >> 7) & 1, wn = (tid >> 6) & 1;

    const bf16* w3b = w3t + (size_t)e * D_MODEL * D_FF;
    const bf16* aSrc[4]; const bf16* bSrc[4]; int dstOff[4];
#pragma unroll
    for (int rd = 0; rd < 4; ++rd) {
        int o = rd * 4096 + tid * 16;
        int r = o >> 7;
        int c2 = ((o >> 4) & 7) ^ (r & 7);
        dstOff[rd] = o;
        aSrc[rd] = H   + (size_t)(rowBase + r) * D_FF + c2 * 8;
        bSrc[rd] = w3b + (size_t)(n0 + r) * D_FF + c2 * 8;
    }

    f32x4 acc[4][4];
#pragma unroll
    for (int m = 0; m < 4; ++m)
#pragma unroll
        for (int n = 0; n < 4; ++n) acc[m][n] = (f32x4){0.f, 0.f, 0.f, 0.f};

    for (int kt = 0; kt < D_FF / 64; ++kt) {
#pragma unroll
        for (int rd = 0; rd < 4; ++rd) {
            gload16(aSrc[rd] + kt * 64, lds + dstOff[rd]);
            gload16(bSrc[rd] + kt * 64, lds + 16384 + dstOff[rd]);
        }
        __syncthreads();
#pragma unroll
        for (int ks = 0; ks < 2; ++ks) {
            bf16x8 af[4], bfr[4];
            int c2 = ks * 4 + (lane >> 4);
#pragma unroll
            for (int m = 0; m < 4; ++m) {
                int r = wm * 64 + m * 16 + (lane & 15);
                af[m] = *(const bf16x8*)(lds + r * 128 + ((c2 ^ (r & 7)) << 4));
            }
#pragma unroll
            for (int n = 0; n < 4; ++n) {
                int r = wn * 64 + n * 16 + (lane & 15);
                bfr[n] = *(const bf16x8*)(lds + 16384 + r * 128 + ((c2 ^ (r & 7)) << 4));
            }
#pragma unroll
            for (int m = 0; m < 4; ++m)
#pragma unroll
                for (int n = 0; n < 4; ++n)
                    acc[m][n] = __builtin_amdgcn_mfma_f32_16x16x32_bf16(af[m], bfr[n], acc[m][n], 0, 0, 0);
        }
        __syncthreads();
    }

#pragma unroll
    for (int m = 0; m < 4; ++m) {
#pragma unroll
        for (int j = 0; j < 4; ++j) {
            int rl = wm * 64 + m * 16 + (lane >> 4) * 4 + j;
            int row = rowBase + rl;
            float wgt = rowW[row];
            bf16* obase = O2 + (size_t)row * D_MODEL + n0 + wn * 64 + (lane & 15);
#pragma unroll
            for (int n = 0; n < 4; ++n)
                obase[n * 16] = (bf16)(wgt * acc[m][n][j]);
        }
    }
}

// ---------------- combine: out[t] = O2[rowOf[t,0]] + O2[rowOf[t,1]] ----------------
__global__ void combine_kernel(const bf16* __restrict__ O2, const int* __restrict__ rowOf,
                               float* __restrict__ out) {
    int t = blockIdx.x;
    int r0 = rowOf[t * 2 + 0], r1 = rowOf[t * 2 + 1];
    int c = threadIdx.x * 4;
    bf16x4 a = *(const bf16x4*)(O2 + (size_t)r0 * D_MODEL + c);
    bf16x4 b = *(const bf16x4*)(O2 + (size_t)r1 * D_MODEL + c);
    float4 o;
    o.x = (float)a[0] + (float)b[0];
    o.y = (float)a[1] + (float)b[1];
    o.z = (float)a[2] + (float)b[2];
    o.w = (float)a[3] + (float)b[3];
    *(float4*)(out + (size_t)t * D_MODEL + c) = o;
}

// ---------------- launch ----------------
extern "C" void kernel_launch(void* const* d_in, const int* in_sizes, int n_in,
                              void* d_out, int out_size, void* d_ws, size_t ws_size,
                              hipStream_t stream) {
    const float* x  = (const float*)d_in[0];
    const int*   ei = (const int*)d_in[1];
    const float* ew = (const float*)d_in[2];
    const float* w1 = (const float*)d_in[3];
    const float* w2 = (const float*)d_in[4];
    const float* w3 = (const float*)d_in[5];
    float* out = (float*)d_out;

    char* w = (char*)d_ws;
    constexpr size_t CTRL_OFF  = 0;
    constexpr size_t TOK_OFF   = 4096;
    constexpr size_t ROWW_OFF  = TOK_OFF + (size_t)MAX_ROWS * 4;       // 73728
    constexpr size_t ROWOF_OFF = ROWW_OFF + (size_t)MAX_ROWS * 4;      // 143360
    constexpr size_t XB_OFF    = ROWOF_OFF + (size_t)T_TOKENS * 2 * 4; // 274432
    constexpr size_t WC_OFF    = XB_OFF + (size_t)T_TOKENS * D_MODEL * 2;       // +16 MB
    constexpr size_t W3T_OFF   = WC_OFF + (size_t)N_EXP * 4096 * 1024 * 2;      // +64 MB
    constexpr size_t H_OFF     = W3T_OFF + (size_t)N_EXP * D_MODEL * D_FF * 2;  // +32 MB
    // O2 (bf16, MAX_ROWS x D_MODEL = 35.7 MB) aliases wc (64 MB), dead after gemm1.
    constexpr size_t O2_OFF    = WC_OFF;

    int*   ctrl    = (int*)(w + CTRL_OFF);
    int*   tokenId = (int*)(w + TOK_OFF);
    float* rowW    = (float*)(w + ROWW_OFF);
    int*   rowOf   = (int*)(w + ROWOF_OFF);
    bf16*  xb      = (bf16*)(w + XB_OFF);
    bf16*  wc      = (bf16*)(w + WC_OFF);
    bf16*  w3t     = (bf16*)(w + W3T_OFF);
    bf16*  H       = (bf16*)(w + H_OFF);
    bf16*  O2      = (bf16*)(w + O2_OFF);

    prep_kernel<<<dim3(8, 32, 29), 256, 0, stream>>>(x, xb, w1, w2, w3, wc, w3t,
                                                     ei, ew, ctrl, tokenId, rowW, rowOf);
    gemm1_kernel<<<MAX_MT * (4096 / 128), 256, 0, stream>>>(xb, wc, H, ctrl, tokenId);
    gemm2_kernel<<<MAX_MT * (D_MODEL / 128), 256, 0, stream>>>(H, w3t, O2, ctrl, rowW);
    combine_kernel<<<T_TOKENS, 256, 0, stream>>>(O2, rowOf, out);
}

// Round 12
// 318.309 us; speedup vs baseline: 1.1408x; 1.1408x over previous
//
#include <hip/hip_runtime.h>
#include <hip/hip_bf16.h>
#include <cstdint>
#include <cstddef>

typedef __bf16 bf16;
typedef __attribute__((ext_vector_type(4))) float f32x4;
typedef __attribute__((ext_vector_type(8))) __bf16 bf16x8;
typedef __attribute__((ext_vector_type(4))) __bf16 bf16x4;

// ---------------- constants ----------------
#define T_TOKENS 8192
#define D_MODEL  1024
#define D_FF     2048
#define N_EXP    8
#define MAX_ROWS 17408   // 16384 + 8*128 padding
#define MAX_MT   136     // max m-tiles of 128 (8 XCD chunks of 17)

// ctrl layout (int indices): numTiles[16], pstart[32..40],
// tileExpert[64..199], tileRow[256..391]

__device__ __forceinline__ void gload16(const void* g, void* l) {
    __builtin_amdgcn_global_load_lds((const __attribute__((address_space(1))) void*)g,
                                     (__attribute__((address_space(3))) void*)l, 16, 0, 0);
}

// ---------------- fused prep: weight transposes + x convert + dispatch build ----
// grid (8,32,29), 256 threads.
//   z in [0,8):   W1 expert z    -> wc even 16-col blocks (mode 1)
//   z in [8,16):  W2 expert z-8  -> wc odd 16-col blocks (mode 2)
//   z in [16,24): W3 expert z-16 -> w3t plain (mode 0)
//   z in [24,28): cvtx, 256 virtual blocks per slice, 8192 elems each
//   z == 28, block (0,0): dispatch build — LATENCY-TOLERANT version: all global
//   loads batched into registers (independent, one drain) before the dependent
//   atomic/store chain; removes the ~50 us serial load->wait tail.
__global__ __launch_bounds__(256)
void prep_kernel(const float* __restrict__ x, bf16* __restrict__ xb,
                 const float* __restrict__ w1, const float* __restrict__ w2,
                 const float* __restrict__ w3, bf16* __restrict__ wc,
                 bf16* __restrict__ w3t,
                 const int* __restrict__ ei, const float* __restrict__ ew,
                 int* __restrict__ ctrl, int* __restrict__ tokenId,
                 float* __restrict__ rowW, int* __restrict__ rowOf) {
    const int z = blockIdx.z;
    const int t = threadIdx.x;

    if (z >= 24) {
        if (z == 28) {
            // ---- dispatch build: single block, register-batched loads ----
            if (blockIdx.x != 0 || blockIdx.y != 0) return;
            __shared__ int lc[N_EXP], cur[N_EXP], ps[N_EXP], padS[N_EXP], padE[N_EXP];
            if (t < N_EXP) { lc[t] = 0; cur[t] = 0; }
            __syncthreads();
            // count: 16 independent int4 loads all in flight, then LDS atomics
            {
                int4 eb[16];
#pragma unroll
                for (int q = 0; q < 16; ++q)
                    eb[q] = *(const int4*)(ei + (q * 256 + t) * 4);
#pragma unroll
                for (int q = 0; q < 16; ++q) {
                    atomicAdd(&lc[eb[q].x], 1);
                    atomicAdd(&lc[eb[q].y], 1);
                    atomicAdd(&lc[eb[q].z], 1);
                    atomicAdd(&lc[eb[q].w], 1);
                }
            }
            __syncthreads();
            if (t == 0) {
                int s = 0, nt = 0;
                for (int e = 0; e < N_EXP; ++e) {
                    ps[e] = s;
                    ctrl[32 + e] = s;
                    int cnt = lc[e];
                    int tiles = (cnt + 127) >> 7;
                    for (int i = 0; i < tiles; ++i) {
                        ctrl[64 + nt] = e; ctrl[256 + nt] = s + (i << 7); ++nt;
                    }
                    padS[e] = s + cnt; padE[e] = s + (tiles << 7);
                    s += tiles << 7;
                }
                ctrl[16] = nt;
            }
            __syncthreads();
            // scatter: 4 chunks of 4x(int4+float4) preloaded (8 loads in flight)
#define SCAT(EV, WV, II) { int e_ = (EV); int pos_ = atomicAdd(&cur[e_], 1); \
                           int r_ = ps[e_] + pos_; tokenId[r_] = (II) >> 1;  \
                           rowW[r_] = (WV); rowOf[II] = r_; }
            for (int c = 0; c < 4; ++c) {
                int4 eb[4]; float4 wb4[4];
#pragma unroll
                for (int q = 0; q < 4; ++q) {
                    int base = ((c * 4 + q) * 256 + t) * 4;
                    eb[q]  = *(const int4*)(ei + base);
                    wb4[q] = *(const float4*)(ew + base);
                }
#pragma unroll
                for (int q = 0; q < 4; ++q) {
                    int base = ((c * 4 + q) * 256 + t) * 4;
                    SCAT(eb[q].x, wb4[q].x, base + 0)
                    SCAT(eb[q].y, wb4[q].y, base + 1)
                    SCAT(eb[q].z, wb4[q].z, base + 2)
                    SCAT(eb[q].w, wb4[q].w, base + 3)
                }
            }
#undef SCAT
            for (int e = 0; e < N_EXP; ++e)
                for (int r = padS[e] + t; r < padE[e]; r += 256) {
                    tokenId[r] = 0; rowW[r] = 0.f;
                }
            return;
        }
        // ---- cvtx: x fp32 -> xb bf16, 32 elems/thread (8192/block) ----
        int bid = (z - 24) * 256 + blockIdx.y * 8 + blockIdx.x;
#pragma unroll
        for (int p = 0; p < 4; ++p) {
            int i = bid * 8192 + p * 2048 + t * 8;
            float4 v0 = *(const float4*)(x + i);
            float4 v1 = *(const float4*)(x + i + 4);
            bf16x8 o;
            o[0] = (bf16)v0.x; o[1] = (bf16)v0.y; o[2] = (bf16)v0.z; o[3] = (bf16)v0.w;
            o[4] = (bf16)v1.x; o[5] = (bf16)v1.y; o[6] = (bf16)v1.z; o[7] = (bf16)v1.w;
            *(bf16x8*)(xb + i) = o;
        }
        return;
    }

    // ---- tconv: fp32 [R][C] -> bf16 [f(C)][R] for one expert, 64x256 strip ----
    int R, C, mode;
    const float* src;
    bf16* dst;
    if (z < 8)       { R = D_MODEL; C = D_FF;    mode = 1; src = w1 + (size_t)z * R * C;        dst = wc  + (size_t)z * 4096 * 1024; }
    else if (z < 16) { R = D_MODEL; C = D_FF;    mode = 2; src = w2 + (size_t)(z - 8) * R * C;  dst = wc  + (size_t)(z - 8) * 4096 * 1024; }
    else             { R = D_FF;    C = D_MODEL; mode = 0; src = w3 + (size_t)(z - 16) * R * C; dst = w3t + (size_t)(z - 16) * D_FF * D_MODEL; }
    const int c0 = blockIdx.x * 256, r0 = blockIdx.y * 64;
    if (c0 >= C || r0 >= R) return;

    __shared__ char tl[16384];   // fp32 [64 rows][16 slots x 16B], source-swizzled

    const int row_[4] = { (0 * 256 + t) >> 4, (1 * 256 + t) >> 4, (2 * 256 + t) >> 4, (3 * 256 + t) >> 4 };
    const int slotc = t & 15;

    for (int st = 0; st < 4; ++st) {
#pragma unroll
        for (int p = 0; p < 4; ++p) {
            int wi = p * 256 + t;
            int row = row_[p];
            int sq = slotc ^ (row & 7) ^ ((row >> 3) & 7);  // source col-quad
            gload16(src + (size_t)(r0 + row) * C + c0 + st * 64 + sq * 4,
                    tl + wi * 16);
        }
        __syncthreads();   // drains vmcnt before reads
#pragma unroll
        for (int p = 0; p < 2; ++p) {
            int wi = p * 256 + t;
            int cl = wi >> 3, rs = wi & 7;
            int c = c0 + st * 64 + cl;
            int dcol = (mode == 0) ? c : (((c >> 4) << 5) + ((mode == 2) ? 16 : 0) + (c & 15));
            bf16x8 ov;
#pragma unroll
            for (int j = 0; j < 8; ++j) {
                int r = rs * 8 + j;
                int sp = (cl >> 2) ^ (r & 7) ^ rs;   // (r>>3)&7 == rs
                float f = *(const float*)(tl + r * 256 + sp * 16 + (cl & 3) * 4);
                ov[j] = (bf16)f;
            }
            *(bf16x8*)(dst + (size_t)dcol * R + r0 + rs * 8) = ov;
        }
        __syncthreads();   // all reads done before next sub-tile overwrites
    }
}

// ---------------- GEMM stage 1: H = silu(X Wc_even) * (X Wc_odd), gathered rows ----
// Combined B: wc [E][4096][1024] bf16 (row = combined col, K contiguous).
// m97-style 2-barrier single-buffer loop; 3 blocks/CU.
// Grid: 1D 4352 blocks, XCD-locality swizzle (xcd = L&7 owns m-tiles chunk).
__global__ __launch_bounds__(256, 3)
void gemm1_kernel(const bf16* __restrict__ xb, const bf16* __restrict__ wc,
                  bf16* __restrict__ H, const int* __restrict__ ctrl,
                  const int* __restrict__ tokenId) {
    const int L = blockIdx.x;
    const int xcd = L & 7;
    const int w = L >> 3;                 // 0..543
    const int mt = xcd * 17 + (w % 17);   // 0..135
    const int n0 = (w / 17) * 128;        // combined-col tile base (0..4095)
    if (mt >= ctrl[16]) return;
    const int e = ctrl[64 + mt];
    const int rowBase = ctrl[256 + mt];

    __shared__ char lds[32768];        // A: [0,16384)  B: [16384,32768)

    const int tid = threadIdx.x, lane = tid & 63;
    const int wm = (tid >> 7) & 1, wn = (tid >> 6) & 1;

    const bf16* wb = wc + (size_t)e * 4096 * 1024;

    const bf16* aSrc[4]; const bf16* bSrc[4]; int dstOff[4];
#pragma unroll
    for (int rd = 0; rd < 4; ++rd) {
        int o = rd * 4096 + tid * 16;
        int r = o >> 7;                    // row 0..127
        int c2 = ((o >> 4) & 7) ^ (r & 7); // pre-swizzled source slot
        dstOff[rd] = o;
        int tok = tokenId[rowBase + r];
        aSrc[rd] = xb + (size_t)tok * D_MODEL + c2 * 8;
        bSrc[rd] = wb + (size_t)(n0 + r) * D_MODEL + c2 * 8;
    }

    f32x4 acc[4][4];
#pragma unroll
    for (int m = 0; m < 4; ++m)
#pragma unroll
        for (int n = 0; n < 4; ++n) acc[m][n] = (f32x4){0.f, 0.f, 0.f, 0.f};

    for (int kt = 0; kt < D_MODEL / 64; ++kt) {
#pragma unroll
        for (int rd = 0; rd < 4; ++rd) {
            gload16(aSrc[rd] + kt * 64, lds + dstOff[rd]);
            gload16(bSrc[rd] + kt * 64, lds + 16384 + dstOff[rd]);
        }
        __syncthreads();   // drains vmcnt before any wave reads
#pragma unroll
        for (int ks = 0; ks < 2; ++ks) {
            bf16x8 af[4], bfr[4];
            int c2 = ks * 4 + (lane >> 4);
#pragma unroll
            for (int m = 0; m < 4; ++m) {
                int r = wm * 64 + m * 16 + (lane & 15);
                af[m] = *(const bf16x8*)(lds + r * 128 + ((c2 ^ (r & 7)) << 4));
            }
#pragma unroll
            for (int n = 0; n < 4; ++n) {
                int r = wn * 64 + n * 16 + (lane & 15);
                bfr[n] = *(const bf16x8*)(lds + 16384 + r * 128 + ((c2 ^ (r & 7)) << 4));
            }
#pragma unroll
            for (int m = 0; m < 4; ++m)
#pragma unroll
                for (int n = 0; n < 4; ++n)
                    acc[m][n] = __builtin_amdgcn_mfma_f32_16x16x32_bf16(af[m], bfr[n], acc[m][n], 0, 0, 0);
        }
        __syncthreads();   // all waves done reading before next stage overwrites
    }

    // epilogue: n-frag pairs (0,1)=(g,v) and (2,3)=(g,v); H col = (n0>>1)+wn*32+(pair?16:0)+(lane&15)
#pragma unroll
    for (int m = 0; m < 4; ++m) {
#pragma unroll
        for (int j = 0; j < 4; ++j) {
            int rl = wm * 64 + m * 16 + (lane >> 4) * 4 + j;
            bf16* hb = H + (size_t)(rowBase + rl) * D_FF + (n0 >> 1) + wn * 32 + (lane & 15);
            {
                float g = acc[m][0][j], v = acc[m][1][j];
                hb[0] = (bf16)((g / (1.f + __expf(-g))) * v);
            }
            {
                float g = acc[m][2][j], v = acc[m][3][j];
                hb[16] = (bf16)((g / (1.f + __expf(-g))) * v);
            }
        }
    }
}

// ---------------- GEMM stage 2: O2[row] = w[row] * (H[row] @ W3) ----------------
// Grid: 1D 1088 blocks. XCD swizzle, n-minor within chunk.
__global__ __launch_bounds__(256, 3)
void gemm2_kernel(const bf16* __restrict__ H, const bf16* __restrict__ w3t,
                  bf16* __restrict__ O2, const int* __restrict__ ctrl,
                  const float* __restrict__ rowW) {
    const int L = blockIdx.x;
    const int xcd = L & 7;
    const int w = L >> 3;                 // 0..135
    const int n0 = (w & 7) * 128;
    const int mt = xcd * 17 + (w >> 3);   // 0..135
    if (mt >= ctrl[16]) return;
    const int e = ctrl[64 + mt];
    const int rowBase = ctrl[256 + mt];

    __shared__ char lds[32768];

    const int tid = threadIdx.x, lane = tid & 63;
    const int wm = (tid >> 7) & 1, wn = (tid >> 6) & 1;

    const bf16* w3b = w3t + (size_t)e * D_MODEL * D_FF;
    const bf16* aSrc[4]; const bf16* bSrc[4]; int dstOff[4];
#pragma unroll
    for (int rd = 0; rd < 4; ++rd) {
        int o = rd * 4096 + tid * 16;
        int r = o >> 7;
        int c2 = ((o >> 4) & 7) ^ (r & 7);
        dstOff[rd] = o;
        aSrc[rd] = H   + (size_t)(rowBase + r) * D_FF + c2 * 8;
        bSrc[rd] = w3b + (size_t)(n0 + r) * D_FF + c2 * 8;
    }

    f32x4 acc[4][4];
#pragma unroll
    for (int m = 0; m < 4; ++m)
#pragma unroll
        for (int n = 0; n < 4; ++n) acc[m][n] = (f32x4){0.f, 0.f, 0.f, 0.f};

    for (int kt = 0; kt < D_FF / 64; ++kt) {
#pragma unroll
        for (int rd = 0; rd < 4; ++rd) {
            gload16(aSrc[rd] + kt * 64, lds + dstOff[rd]);
            gload16(bSrc[rd] + kt * 64, lds + 16384 + dstOff[rd]);
        }
        __syncthreads();
#pragma unroll
        for (int ks = 0; ks < 2; ++ks) {
            bf16x8 af[4], bfr[4];
            int c2 = ks * 4 + (lane >> 4);
#pragma unroll
            for (int m = 0; m < 4; ++m) {
                int r = wm * 64 + m * 16 + (lane & 15);
                af[m] = *(const bf16x8*)(lds + r * 128 + ((c2 ^ (r & 7)) << 4));
            }
#pragma unroll
            for (int n = 0; n < 4; ++n) {
                int r = wn * 64 + n * 16 + (lane & 15);
                bfr[n] = *(const bf16x8*)(lds + 16384 + r * 128 + ((c2 ^ (r & 7)) << 4));
            }
#pragma unroll
            for (int m = 0; m < 4; ++m)
#pragma unroll
                for (int n = 0; n < 4; ++n)
                    acc[m][n] = __builtin_amdgcn_mfma_f32_16x16x32_bf16(af[m], bfr[n], acc[m][n], 0, 0, 0);
        }
        __syncthreads();
    }

#pragma unroll
    for (int m = 0; m < 4; ++m) {
#pragma unroll
        for (int j = 0; j < 4; ++j) {
            int rl = wm * 64 + m * 16 + (lane >> 4) * 4 + j;
            int row = rowBase + rl;
            float wgt = rowW[row];
            bf16* obase = O2 + (size_t)row * D_MODEL + n0 + wn * 64 + (lane & 15);
#pragma unroll
            for (int n = 0; n < 4; ++n)
                obase[n * 16] = (bf16)(wgt * acc[m][n][j]);
        }
    }
}

// ---------------- combine: out[t] = O2[rowOf[t,0]] + O2[rowOf[t,1]] ----------------
__global__ void combine_kernel(const bf16* __restrict__ O2, const int* __restrict__ rowOf,
                               float* __restrict__ out) {
    int t = blockIdx.x;
    int r0 = rowOf[t * 2 + 0], r1 = rowOf[t * 2 + 1];
    int c = threadIdx.x * 4;
    bf16x4 a = *(const bf16x4*)(O2 + (size_t)r0 * D_MODEL + c);
    bf16x4 b = *(const bf16x4*)(O2 + (size_t)r1 * D_MODEL + c);
    float4 o;
    o.x = (float)a[0] + (float)b[0];
    o.y = (float)a[1] + (float)b[1];
    o.z = (float)a[2] + (float)b[2];
    o.w = (float)a[3] + (float)b[3];
    *(float4*)(out + (size_t)t * D_MODEL + c) = o;
}

// ---------------- launch ----------------
extern "C" void kernel_launch(void* const* d_in, const int* in_sizes, int n_in,
                              void* d_out, int out_size, void* d_ws, size_t ws_size,
                              hipStream_t stream) {
    const float* x  = (const float*)d_in[0];
    const int*   ei = (const int*)d_in[1];
    const float* ew = (const float*)d_in[2];
    const float* w1 = (const float*)d_in[3];
    const float* w2 = (const float*)d_in[4];
    const float* w3 = (const float*)d_in[5];
    float* out = (float*)d_out;

    char* w = (char*)d_ws;
    constexpr size_t CTRL_OFF  = 0;
    constexpr size_t TOK_OFF   = 4096;
    constexpr size_t ROWW_OFF  = TOK_OFF + (size_t)MAX_ROWS * 4;       // 73728
    constexpr size_t ROWOF_OFF = ROWW_OFF + (size_t)MAX_ROWS * 4;      // 143360
    constexpr size_t XB_OFF    = ROWOF_OFF + (size_t)T_TOKENS * 2 * 4; // 274432
    constexpr size_t WC_OFF    = XB_OFF + (size_t)T_TOKENS * D_MODEL * 2;       // +16 MB
    constexpr size_t W3T_OFF   = WC_OFF + (size_t)N_EXP * 4096 * 1024 * 2;      // +64 MB
    constexpr size_t H_OFF     = W3T_OFF + (size_t)N_EXP * D_MODEL * D_FF * 2;  // +32 MB
    // O2 (bf16, MAX_ROWS x D_MODEL = 35.7 MB) aliases wc (64 MB), dead after gemm1.
    constexpr size_t O2_OFF    = WC_OFF;

    int*   ctrl    = (int*)(w + CTRL_OFF);
    int*   tokenId = (int*)(w + TOK_OFF);
    float* rowW    = (float*)(w + ROWW_OFF);
    int*   rowOf   = (int*)(w + ROWOF_OFF);
    bf16*  xb      = (bf16*)(w + XB_OFF);
    bf16*  wc      = (bf16*)(w + WC_OFF);
    bf16*  w3t     = (bf16*)(w + W3T_OFF);
    bf16*  H       = (bf16*)(w + H_OFF);
    bf16*  O2      = (bf16*)(w + O2_OFF);

    prep_kernel<<<dim3(8, 32, 29), 256, 0, stream>>>(x, xb, w1, w2, w3, wc, w3t,
                                                     ei, ew, ctrl, tokenId, rowW, rowOf);
    gemm1_kernel<<<MAX_MT * (4096 / 128), 256, 0, stream>>>(xb, wc, H, ctrl, tokenId);
    gemm2_kernel<<<MAX_MT * (D_MODEL / 128), 256, 0, stream>>>(H, w3t, O2, ctrl, rowW);
    combine_kernel<<<T_TOKENS, 256, 0, stream>>>(O2, rowOf, out);
}